// Round 8
// baseline (4273.101 us; speedup 1.0000x reference)
//
#include <hip/hip_runtime.h>

// KoopmanLQR via structured doubling (SDA): 8 iterations replace 255 Riccati steps.
// Round 10: fence-free grid phases. Rounds 7/9 showed ~20us/barrier REGARDLESS of
// arrival mechanism -> the cost is the agent release/acquire fence pair (buffer_wbl2
// + buffer_inv: full per-XCD L2 writeback/invalidate) plus cold-cache restaging.
// Fix: ALL shared-matrix loads/stores in k_sda use agent-scope RELAXED atomics
// (sc1 -> read/write through to coherent L3). Data never lives in stale L2 =>
// the grid barrier needs NO fences at all. Math identical to the passing kernel.
// K=256, U=64, BATCH=131072. All fp32.

#define KD 256
#define UD 64
#define NB 131072
#define NWG 50   // grid size (max phase width = upd1's 50); all WGs co-resident

// ---------------- coherent (L2-bypass, sc1) scalar access helpers ----------------
__device__ __forceinline__ float ldc(const float* p) {
    return __hip_atomic_load(p, __ATOMIC_RELAXED, __HIP_MEMORY_SCOPE_AGENT);
}
__device__ __forceinline__ void stc(float* p, float v) {
    __hip_atomic_store(p, v, __ATOMIC_RELAXED, __HIP_MEMORY_SCOPE_AGENT);
}

// ---------------- fence-free parallel-flag grid barrier ----------------
// bar[0] = global generation; bar[16 + 16*i] = WG i's arrival flag (64B-spaced).
// All shared data moves via sc1 (L3-coherent), so no acquire/release fences needed:
// __syncthreads() drains vmcnt => this WG's sc1 stores are in L3 before the flag.
__device__ __forceinline__ void gbar(unsigned* bar, unsigned gen) {
    __syncthreads();
    if (threadIdx.x == 0)
        __hip_atomic_store(&bar[16 + 16 * blockIdx.x], gen, __ATOMIC_RELAXED,
                           __HIP_MEMORY_SCOPE_AGENT);
    if (blockIdx.x == 0) {
        if (threadIdx.x < NWG) {
            while (__hip_atomic_load(&bar[16 + 16 * threadIdx.x], __ATOMIC_RELAXED,
                                     __HIP_MEMORY_SCOPE_AGENT) < gen)
                __builtin_amdgcn_s_sleep(1);
        }
        __syncthreads();   // all 50 flags observed
        if (threadIdx.x == 0)
            __hip_atomic_store(&bar[0], gen, __ATOMIC_RELAXED, __HIP_MEMORY_SCOPE_AGENT);
        __syncthreads();
    } else {
        if (threadIdx.x == 0) {
            while (__hip_atomic_load(&bar[0], __ATOMIC_RELAXED,
                                     __HIP_MEMORY_SCOPE_AGENT) < gen)
                __builtin_amdgcn_s_sleep(1);
        }
        __syncthreads();
    }
}

// ---------------- 64-deep 4x4-microkernel MAC on staged LDS tiles ----------------
__device__ __forceinline__ void mac64(const float* At, const float* Bt,
                                      float acc[4][4], int tb, int tj) {
    for (int kl = 0; kl < 64; ++kl) {
        float4 a4 = *(const float4*)&At[kl * 68 + 4 * tb];
        float4 b4 = *(const float4*)&Bt[kl * 68 + 4 * tj];
        acc[0][0] += a4.x * b4.x; acc[0][1] += a4.x * b4.y; acc[0][2] += a4.x * b4.z; acc[0][3] += a4.x * b4.w;
        acc[1][0] += a4.y * b4.x; acc[1][1] += a4.y * b4.y; acc[1][2] += a4.y * b4.z; acc[1][3] += a4.y * b4.w;
        acc[2][0] += a4.z * b4.x; acc[2][1] += a4.z * b4.y; acc[2][2] += a4.z * b4.z; acc[2][3] += a4.z * b4.w;
        acc[3][0] += a4.w * b4.x; acc[3][1] += a4.w * b4.y; acc[3][2] += a4.w * b4.z; acc[3][3] += a4.w * b4.w;
    }
}

// ---------------- generic 64x64-tile matmul (K=256), sc1 global access ----------------
// C[bi,bj] = op(A)*op(B) (+C0) (+I). All matrices 256x256 row-major ld=256.
__device__ __forceinline__ void mm_tile(float* At, float* Bt,
                                        const float* Aop, const float* Bop,
                                        const float* C0, float* C,
                                        int tra, int trb, int addI, int bi, int bj) {
    int tid = threadIdx.x;
    int tb = tid >> 4, tj = tid & 15;
    float acc[4][4] = {{0.f}};
    for (int kc = 0; kc < 4; ++kc) {
        __syncthreads();
        if (!tra) {
            for (int e = tid; e < 4096; e += 256) {
                int r = e >> 6, c = e & 63;
                At[c * 68 + r] = ldc(&Aop[(bi * 64 + r) * 256 + kc * 64 + c]);
            }
        } else {
            for (int e = tid; e < 4096; e += 256) {
                int r = e & 63, c = e >> 6;
                At[c * 68 + r] = ldc(&Aop[(kc * 64 + c) * 256 + bi * 64 + r]);
            }
        }
        if (!trb) {
            for (int e = tid; e < 4096; e += 256) {
                int j2 = e & 63, c = e >> 6;
                Bt[c * 68 + j2] = ldc(&Bop[(kc * 64 + c) * 256 + bj * 64 + j2]);
            }
        } else {
            for (int e = tid; e < 4096; e += 256) {
                int j2 = e >> 6, c = e & 63;
                Bt[c * 68 + j2] = ldc(&Bop[(bj * 64 + j2) * 256 + kc * 64 + c]);
            }
        }
        __syncthreads();
        mac64(At, Bt, acc, tb, tj);
    }
    for (int ii = 0; ii < 4; ++ii)
        for (int jj = 0; jj < 4; ++jj) {
            int gi = bi * 64 + 4 * tb + ii, gj = bj * 64 + 4 * tj + jj;
            float vv = acc[ii][jj];
            if (C0) vv += ldc(&C0[gi * 256 + gj]);
            if (addI && gi == gj) vv += 1.f;
            stc(&C[gi * 256 + gj], vv);
        }
}

// ======================= init (also zeros the barrier state) =======================
__global__ void k_init(const float* __restrict__ ql, const float* __restrict__ rl,
                       const float* __restrict__ gg, const float* __restrict__ A,
                       float* __restrict__ H, float* __restrict__ F,
                       float* __restrict__ a, float* __restrict__ h,
                       float* __restrict__ rinv, unsigned* __restrict__ bar) {
    int idx = blockIdx.x * 256 + threadIdx.x;
    int i = idx >> 8, j = idx & 255;
    H[idx] = (i == j) ? expf(ql[i]) : 0.f;
    F[idx] = A[idx];
    if (idx < 256) { h[idx] = expf(ql[idx]) * gg[idx]; a[idx] = 0.f; }
    if (idx < 64) rinv[idx] = expf(-rl[idx]);
    if (idx < 16 + 16 * NWG) bar[idx] = 0u;
}

// ======================= the whole SDA loop, one kernel, fence-free barriers =======================
__global__ __launch_bounds__(256) void k_sda(
    const float* A, const float* Bm,
    float* G, float* H, float* F0, float* F1, float* M,
    float* XF, float* XG, float* HXF, float* Pm,
    float* a, float* h, float* t, float* z, float* wv, float* av,
    const float* rinv, unsigned* bar) {
    __shared__ __align__(16) float SA[64 * 68];
    __shared__ __align__(16) float SB[64 * 68];
    const int w = blockIdx.x;
    const int tid = threadIdx.x;
    const int tb = tid >> 4, tj = tid & 15;
    unsigned gen = 0;
    float* Trs = HXF;  // scratch aliases: dead during inversion phases
    float* Ncs = Pm;

    // ---- G = B R^-1 B^T (16 tile WGs, K=64). Bm/rinv are read-only: cached loads ok ----
    if (w < 16) {
        int bi = w >> 2, bj = w & 3;
        for (int e = tid; e < 4096; e += 256) {
            int r = e >> 6, u = e & 63;
            SA[u * 68 + r] = Bm[(bi * 64 + r) * 64 + u] * rinv[u];
        }
        for (int e = tid; e < 4096; e += 256) {
            int c = e >> 6, u = e & 63;
            SB[u * 68 + c] = Bm[(bj * 64 + c) * 64 + u];
        }
        __syncthreads();
        float acc[4][4] = {{0.f}};
        mac64(SA, SB, acc, tb, tj);
        for (int ii = 0; ii < 4; ++ii)
            for (int jj = 0; jj < 4; ++jj)
                stc(&G[(bi * 64 + 4 * tb + ii) * 256 + bj * 64 + 4 * tj + jj], acc[ii][jj]);
    }
    gbar(bar, ++gen);

    float* Fc = F0; float* Fn = F1;
    for (int it = 0; it < 8; ++it) {
        // ================= M = I + G*H ; t = a - G*h =================
        if (w < 16) {
            mm_tile(SA, SB, G, H, nullptr, M, 0, 0, 1, w >> 2, w & 3);
        } else if (w == 16) {
            SA[tid] = ldc(&h[tid]);
            __syncthreads();
            float acc = ldc(&a[tid]);
            for (int j = 0; j < 256; ++j) acc -= ldc(&G[j * 256 + tid]) * SA[j];  // G symmetric
            stc(&t[tid], acc);
        }
        gbar(bar, ++gen);

        // ================= in-place block Gauss-Jordan: M -> M^{-1} =================
        // sweep step J: S=inv(M[J][J]); Tr=S*Mold[J][c]; Ncol=-Mold[r][J]*S;
        // M[r][c] += Ncol[r]*Mold[J][c]; M[r][J]=Ncol; M[J][c]=Tr; M[J][J]=S.
        // Pivot row J's new value (Tr) stays in scratch, materialized next P2a.
        for (int J = 0; J < 4; ++J) {
            // ---- P2a: WG0 inverts diag block; WGs 1-3 materialize prev pivot row ----
            if (w == 0) {
                float* W = SA;                 // 64x64, stride 68
                float* T16 = SB;               // 16x64, stride 68
                float* C16 = SB + 1088;        // 64x16, stride 20
                float* Wd  = SB + 2368;        // 16x16, stride 20
                for (int e = tid; e < 4096; e += 256) {
                    int r = e >> 6, c = e & 63;
                    W[r * 68 + c] = ldc(&M[(64 * J + r) * 256 + 64 * J + c]);
                }
                __syncthreads();
                for (int Js = 0; Js < 4; ++Js) {
                    if (tid < 64) {  // level-1: 16x16 scalar sweep, 1 wave, lockstep
                        int r = tid >> 2, s = tid & 3;
                        for (int q = 0; q < 4; ++q) {
                            int e2 = tid * 4 + q, rr = e2 >> 4, cc = e2 & 15;
                            Wd[rr * 20 + cc] = W[(16 * Js + rr) * 68 + 16 * Js + cc];
                        }
                        for (int j = 0; j < 16; ++j) {
                            float piv = Wd[j * 20 + j];
                            float rp = 1.f / piv;
                            float4 pr = *(const float4*)&Wd[j * 20 + 4 * s];
                            float colv = Wd[r * 20 + j];
                            float4 mi = *(const float4*)&Wd[r * 20 + 4 * s];
                            float t0 = pr.x * rp, t1 = pr.y * rp, t2 = pr.z * rp, t3 = pr.w * rp;
                            float m0, m1, m2, m3;
                            if (r == j) { m0 = t0; m1 = t1; m2 = t2; m3 = t3; }
                            else { m0 = mi.x - colv * t0; m1 = mi.y - colv * t1;
                                   m2 = mi.z - colv * t2; m3 = mi.w - colv * t3; }
                            if ((j >> 2) == s) {
                                float cv = (r == j) ? rp : -colv * rp;
                                int q = j & 3;
                                if (q == 0) m0 = cv; else if (q == 1) m1 = cv;
                                else if (q == 2) m2 = cv; else m3 = cv;
                            }
                            *(float4*)&Wd[r * 20 + 4 * s] = make_float4(m0, m1, m2, m3);
                        }
                        for (int q = 0; q < 4; ++q) {
                            int e2 = tid * 4 + q, rr = e2 >> 4, cc = e2 & 15;
                            W[(16 * Js + rr) * 68 + 16 * Js + cc] = Wd[rr * 20 + cc];
                        }
                    }
                    __syncthreads();
                    // phase a: T16 = S16 * W[Js-rows][*] ; C16 = W[*][Js-cols] * S16
                    for (int e = tid; e < 1024; e += 256) {
                        int r = e >> 6, c = e & 63;
                        float s0 = 0.f;
                        for (int k = 0; k < 16; ++k)
                            s0 += W[(16 * Js + r) * 68 + 16 * Js + k] * W[(16 * Js + k) * 68 + c];
                        T16[r * 68 + c] = s0;
                    }
                    for (int e = tid; e < 1024; e += 256) {
                        int r2 = e >> 4, c2 = e & 15;
                        float s0 = 0.f;
                        for (int k = 0; k < 16; ++k)
                            s0 += W[r2 * 68 + 16 * Js + k] * W[(16 * Js + k) * 68 + 16 * Js + c2];
                        C16[r2 * 20 + c2] = s0;
                    }
                    __syncthreads();
                    // phase b: interior update (reads OLD col Js)
                    for (int e = tid; e < 1024; e += 256) {
                        int r = e >> 4, c4 = (e & 15) * 4;
                        if ((r >> 4) != Js && (c4 >> 4) != Js) {
                            float4 x = *(const float4*)&W[r * 68 + c4];
                            for (int k = 0; k < 16; ++k) {
                                float avv = W[r * 68 + 16 * Js + k];
                                const float4 t4 = *(const float4*)&T16[k * 68 + c4];
                                x.x -= avv * t4.x; x.y -= avv * t4.y;
                                x.z -= avv * t4.z; x.w -= avv * t4.w;
                            }
                            *(float4*)&W[r * 68 + c4] = x;
                        }
                    }
                    __syncthreads();
                    // phase c: pivot row / pivot column
                    for (int e = tid; e < 1024; e += 256) {
                        int r = e >> 6, c = e & 63;
                        if ((c >> 4) != Js) W[(16 * Js + r) * 68 + c] = T16[r * 68 + c];
                    }
                    for (int e = tid; e < 1024; e += 256) {
                        int r2 = e >> 4, c2 = e & 15;
                        if ((r2 >> 4) != Js) W[r2 * 68 + 16 * Js + c2] = -C16[r2 * 20 + c2];
                    }
                    __syncthreads();
                }
                // write S = inv(M[J][J]) back to global
                for (int e = tid; e < 4096; e += 256) {
                    int r = e >> 6, c = e & 63;
                    stc(&M[(64 * J + r) * 256 + 64 * J + c], W[r * 68 + c]);
                }
            } else if (J > 0 && w <= 3) {
                // materialize row J-1 (final value = Trs) into M
                int i = w - 1, Jp = J - 1;
                int cb = i + (i >= Jp ? 1 : 0);
                for (int e = tid; e < 4096; e += 256)
                    stc(&M[(64 * Jp + (e >> 6)) * 256 + 64 * cb + (e & 63)],
                        ldc(&Trs[i * 4096 + e]));
            }
            gbar(bar, ++gen);
            // ---- P2b: Tr row blocks (scratch) + Ncol column blocks (scratch + M) ----
            if (w < 3) {
                int cb = w + (w >= J ? 1 : 0);
                for (int e = tid; e < 4096; e += 256) {
                    int r = e >> 6, k = e & 63;
                    SA[k * 68 + r] = ldc(&M[(64 * J + r) * 256 + 64 * J + k]);   // S^T stage
                }
                for (int e = tid; e < 4096; e += 256) {
                    int k = e >> 6, c = e & 63;
                    SB[k * 68 + c] = ldc(&M[(64 * J + k) * 256 + 64 * cb + c]);  // old row J
                }
                __syncthreads();
                float acc[4][4] = {{0.f}};
                mac64(SA, SB, acc, tb, tj);
                for (int ii = 0; ii < 4; ++ii)
                    for (int jj = 0; jj < 4; ++jj)
                        stc(&Trs[w * 4096 + (4 * tb + ii) * 64 + 4 * tj + jj], acc[ii][jj]);
            } else if (w < 6) {
                int i = w - 3;
                int rb = i + (i >= J ? 1 : 0);
                for (int e = tid; e < 4096; e += 256) {
                    int r = e >> 6, k = e & 63;
                    SA[k * 68 + r] = ldc(&M[(64 * rb + r) * 256 + 64 * J + k]);  // old col J
                }
                for (int e = tid; e < 4096; e += 256) {
                    int k = e >> 6, c = e & 63;
                    SB[k * 68 + c] = ldc(&M[(64 * J + k) * 256 + 64 * J + c]);   // S
                }
                __syncthreads();
                float acc[4][4] = {{0.f}};
                mac64(SA, SB, acc, tb, tj);
                for (int ii = 0; ii < 4; ++ii)
                    for (int jj = 0; jj < 4; ++jj) {
                        float v = -acc[ii][jj];
                        stc(&Ncs[i * 4096 + (4 * tb + ii) * 64 + 4 * tj + jj], v);
                        stc(&M[(64 * rb + 4 * tb + ii) * 256 + 64 * J + 4 * tj + jj], v);
                    }
            }
            gbar(bar, ++gen);
            // ---- P2c: interior rank-64 update: M[rb][cb] += Ncol[rb] * Mold[J][cb] ----
            if (w < 9) {
                int ri = w / 3, ci = w % 3;
                int rb = ri + (ri >= J ? 1 : 0), cb = ci + (ci >= J ? 1 : 0);
                for (int e = tid; e < 4096; e += 256) {
                    int r = e >> 6, k = e & 63;
                    SA[k * 68 + r] = ldc(&Ncs[ri * 4096 + r * 64 + k]);
                }
                for (int e = tid; e < 4096; e += 256) {
                    int k = e >> 6, c = e & 63;
                    SB[k * 68 + c] = ldc(&M[(64 * J + k) * 256 + 64 * cb + c]); // old row J
                }
                __syncthreads();
                float acc[4][4] = {{0.f}};
                mac64(SA, SB, acc, tb, tj);
                for (int ii = 0; ii < 4; ++ii)
                    for (int jj = 0; jj < 4; ++jj) {
                        float* mp = &M[(64 * rb + 4 * tb + ii) * 256 + 64 * cb + 4 * tj + jj];
                        stc(mp, ldc(mp) + acc[ii][jj]);
                    }
            }
            gbar(bar, ++gen);
        }
        // ---- P2d: materialize final pivot row (J=3) ----
        if (w < 3) {
            for (int e = tid; e < 4096; e += 256)
                stc(&M[(192 + (e >> 6)) * 256 + 64 * w + (e & 63)],
                    ldc(&Trs[w * 4096 + e]));
        }
        gbar(bar, ++gen);

        // ================= apply: XF = M^-1 F, XG = M^-1 G, z = M^-1 t =================
        if (w < 16) {
            mm_tile(SA, SB, M, Fc, nullptr, XF, 0, 0, 0, w >> 2, w & 3);
        } else if (w < 32) {
            mm_tile(SA, SB, M, G, nullptr, XG, 0, 0, 0, (w - 16) >> 2, (w - 16) & 3);
        } else if (w == 32) {
            SA[tid] = ldc(&t[tid]);
            __syncthreads();
            float acc = 0.f;
            for (int j = 0; j < 256; ++j)
                acc += ldc(&M[tid * 256 + j]) * SA[j];
            stc(&z[tid], acc);
        }
        gbar(bar, ++gen);

        // ================= upd1 =================
        if (w < 16) {
            mm_tile(SA, SB, Fc, XF, nullptr, Fn, 0, 0, 0, w >> 2, w & 3);
        } else if (w < 32) {
            mm_tile(SA, SB, H, XF, nullptr, HXF, 0, 0, 0, (w - 16) >> 2, (w - 16) & 3);
        } else if (w < 48) {
            mm_tile(SA, SB, Fc, XG, nullptr, Pm, 0, 0, 0, (w - 32) >> 2, (w - 32) & 3);
        } else if (w == 48) {
            SA[tid] = ldc(&z[tid]);
            __syncthreads();
            float acc = ldc(&h[tid]);
            for (int j = 0; j < 256; ++j) acc += ldc(&H[j * 256 + tid]) * SA[j];  // H symmetric
            stc(&wv[tid], acc);
        } else if (w == 49) {
            SA[tid] = ldc(&z[tid]);
            __syncthreads();
            float acc = 0.f;
            for (int j = 0; j < 256; ++j) acc += ldc(&Fc[tid * 256 + j]) * SA[j];
            stc(&av[tid], acc);
        }
        gbar(bar, ++gen);

        // ================= upd2 =================
        if (w < 16) {
            mm_tile(SA, SB, Fc, HXF, H, H, 1, 0, 0, w >> 2, w & 3);
        } else if (w < 32) {
            mm_tile(SA, SB, Pm, Fc, G, G, 0, 1, 0, (w - 16) >> 2, (w - 16) & 3);
        } else if (w == 32) {
            SA[tid] = ldc(&wv[tid]);
            __syncthreads();
            float acc = ldc(&h[tid]);
            for (int p = 0; p < 256; ++p) acc += ldc(&Fc[p * 256 + tid]) * SA[p];
            stc(&h[tid], acc);
            stc(&a[tid], ldc(&a[tid]) + ldc(&av[tid]));
        }
        gbar(bar, ++gen);
        float* tmp = Fc; Fc = Fn; Fn = tmp;
    }
}

// ======================= final gains =======================
__global__ void k_btv(const float* __restrict__ B, const float* __restrict__ V,
                      const float* __restrict__ v, float* __restrict__ BtV,
                      float* __restrict__ btv) {
    if (blockIdx.x < 64) {
        int idx = blockIdx.x * 256 + threadIdx.x;
        int i = idx >> 8, q = idx & 255;
        float acc = 0.f;
        for (int p2 = 0; p2 < 256; ++p2) acc += B[p2 * 64 + i] * V[p2 * 256 + q];
        BtV[idx] = acc;
    } else if (threadIdx.x < 64) {
        int i = threadIdx.x;
        float acc = 0.f;
        for (int p2 = 0; p2 < 256; ++p2) acc += B[p2 * 64 + i] * v[p2];
        btv[i] = acc;
    }
}

__global__ void k_SVuu(const float* __restrict__ A, const float* __restrict__ B,
                       const float* __restrict__ rl, const float* __restrict__ BtV,
                       float* __restrict__ S, float* __restrict__ Vuu) {
    int bx = blockIdx.x;
    if (bx < 64) {
        int idx = bx * 256 + threadIdx.x;
        int i = idx >> 8, q = idx & 255;
        float acc = 0.f;
        for (int p2 = 0; p2 < 256; ++p2) acc += BtV[i * 256 + p2] * A[p2 * 256 + q];
        S[idx] = acc;
    } else {
        int tdx = (bx - 64) * 256 + threadIdx.x;
        int i = tdx >> 6, j = tdx & 63;
        float acc = (i == j) ? expf(rl[i]) : 0.f;
        for (int p2 = 0; p2 < 256; ++p2) acc += BtV[i * 256 + p2] * B[p2 * 64 + j];
        Vuu[tdx] = acc;
    }
}

// 64x64 SPD Cholesky, 1 WG
__global__ void k_chol(const float* __restrict__ Vuu, float* __restrict__ L) {
    __shared__ float Msh[64 * 64];
    int tid = threadIdx.x;
    for (int e = tid; e < 4096; e += 256) Msh[e] = Vuu[e];
    __syncthreads();
    int i = tid & 63, c = tid >> 6;
    for (int j = 0; j < 64; ++j) {
        if (tid == 0) Msh[j * 64 + j] = sqrtf(Msh[j * 64 + j]);
        __syncthreads();
        float d = Msh[j * 64 + j];
        if (c == 0 && i > j) Msh[i * 64 + j] /= d;
        __syncthreads();
        if (i > j) {
            float lij = Msh[i * 64 + j];
            for (int k = j + 1 + c; k <= i; k += 4)
                Msh[i * 64 + k] -= lij * Msh[k * 64 + j];
        }
        __syncthreads();
    }
    for (int e = tid; e < 4096; e += 256) {
        int r = e >> 6, k = e & 63;
        L[e] = (k <= r) ? Msh[e] : 0.f;
    }
}

// K0 = Vuu^-1 S, k0 = Vuu^-1 btv (fwd+bwd via wave shuffles)
__global__ void k_solveK(const float* __restrict__ L, const float* __restrict__ S,
                         const float* __restrict__ btv,
                         float* __restrict__ K0, float* __restrict__ k0) {
    int w = (blockIdx.x * 256 + threadIdx.x) >> 6;
    int lane = threadIdx.x & 63;
    if (w >= 257) return;
    float x = (w < 256) ? S[lane * 256 + w] : btv[lane];
    for (int a = 0; a < 64; ++a) {
        float val = (lane < a) ? L[a * 64 + lane] * x : 0.f;
        for (int o = 32; o > 0; o >>= 1) val += __shfl_xor(val, o, 64);
        float xa = (__shfl(x, a, 64) - val) / L[a * 64 + a];
        if (lane == a) x = xa;
    }
    for (int a = 63; a >= 0; --a) {
        float val = (lane > a) ? L[lane * 64 + a] * x : 0.f;
        for (int o = 32; o > 0; o >>= 1) val += __shfl_xor(val, o, 64);
        float xa = (__shfl(x, a, 64) - val) / L[a * 64 + a];
        if (lane == a) x = xa;
    }
    if (w < 256) K0[lane * 256 + w] = x;
    else k0[lane] = x;
}

// u = clip(-g0 @ K0^T + k0)
__global__ __launch_bounds__(256) void k_gemm(const float* __restrict__ g0,
                                              const float* __restrict__ K0,
                                              const float* __restrict__ k0,
                                              float* __restrict__ out) {
    __shared__ __align__(16) float g0t[64 * 68];
    __shared__ __align__(16) float kt[64 * 68];
    int tid = threadIdx.x;
    int base = blockIdx.x * 64;
    int tb = tid >> 4;
    int tj = tid & 15;
    float acc[4][4] = {{0.f}};
    for (int kc = 0; kc < 4; ++kc) {
        __syncthreads();
        for (int e = tid; e < 4096; e += 256) {
            int r = e >> 6, kl = e & 63;
            g0t[kl * 68 + r] = g0[(base + r) * 256 + kc * 64 + kl];
        }
        for (int e = tid; e < 4096; e += 256) {
            int j = e >> 6, kl = e & 63;
            kt[kl * 68 + j] = K0[j * 256 + kc * 64 + kl];
        }
        __syncthreads();
        for (int kl = 0; kl < 64; ++kl) {
            float4 g = *(const float4*)&g0t[kl * 68 + 4 * tb];
            float4 kv = *(const float4*)&kt[kl * 68 + 4 * tj];
            acc[0][0] += g.x * kv.x; acc[0][1] += g.x * kv.y; acc[0][2] += g.x * kv.z; acc[0][3] += g.x * kv.w;
            acc[1][0] += g.y * kv.x; acc[1][1] += g.y * kv.y; acc[1][2] += g.y * kv.z; acc[1][3] += g.y * kv.w;
            acc[2][0] += g.z * kv.x; acc[2][1] += g.z * kv.y; acc[2][2] += g.z * kv.z; acc[2][3] += g.z * kv.w;
            acc[3][0] += g.w * kv.x; acc[3][1] += g.w * kv.y; acc[3][2] += g.w * kv.z; acc[3][3] += g.w * kv.w;
        }
    }
    float c0 = k0[4 * tj + 0], c1 = k0[4 * tj + 1], c2 = k0[4 * tj + 2], c3 = k0[4 * tj + 3];
    for (int i = 0; i < 4; ++i) {
        float4 o;
        o.x = fminf(1.0f, fmaxf(-1.0f, c0 - acc[i][0]));
        o.y = fminf(1.0f, fmaxf(-1.0f, c1 - acc[i][1]));
        o.z = fminf(1.0f, fmaxf(-1.0f, c2 - acc[i][2]));
        o.w = fminf(1.0f, fmaxf(-1.0f, c3 - acc[i][3]));
        *(float4*)&out[(base + 4 * tb + i) * 64 + 4 * tj] = o;
    }
}

extern "C" void kernel_launch(void* const* d_in, const int* in_sizes, int n_in,
                              void* d_out, int out_size, void* d_ws, size_t ws_size,
                              hipStream_t stream) {
    const float* g0 = (const float*)d_in[0];
    const float* A  = (const float*)d_in[1];
    const float* B  = (const float*)d_in[2];
    const float* ql = (const float*)d_in[3];
    const float* rl = (const float*)d_in[4];
    const float* gg = (const float*)d_in[5];
    // d_in[6] = T == 256, hardcoded (log2 T = 8 doublings).

    float* ws = (float*)d_ws;
    float* G    = ws;             // 65536
    float* H    = G    + 65536;
    float* F0   = H    + 65536;
    float* F1   = F0   + 65536;
    float* M    = F1   + 65536;
    float* XF   = M    + 65536;
    float* XG   = XF   + 65536;
    float* HXF  = XG   + 65536;   // aliased as Trs scratch during inversion
    float* P    = HXF  + 65536;   // aliased as Ncs scratch during inversion
    float* BtV  = P    + 65536;   // 16384
    float* S    = BtV  + 16384;   // 16384
    float* K0   = S    + 16384;   // 16384
    float* Vuu  = K0   + 16384;   // 4096
    float* L64  = Vuu  + 4096;    // 4096
    float* a    = L64  + 4096;    // 256
    float* h    = a    + 256;     // 256
    float* t    = h    + 256;     // 256
    float* z    = t    + 256;     // 256
    float* wv   = z    + 256;     // 256
    float* av   = wv   + 256;     // 256
    float* rinv = av   + 256;     // 64
    float* btv  = rinv + 64;      // 64
    float* k0v  = btv  + 64;      // 64
    unsigned* bar = (unsigned*)(k0v + 64);  // 16 + 16*NWG u32 barrier state

    k_init<<<256, 256, 0, stream>>>(ql, rl, gg, A, H, F0, a, h, rinv, bar);
    k_sda<<<NWG, 256, 0, stream>>>(A, B, G, H, F0, F1, M, XF, XG, HXF, P,
                                   a, h, t, z, wv, av, rinv, bar);

    // gains from V = H_8, v = h_8
    k_btv<<<65, 256, 0, stream>>>(B, H, h, BtV, btv);
    k_SVuu<<<80, 256, 0, stream>>>(A, B, rl, BtV, S, Vuu);
    k_chol<<<1, 256, 0, stream>>>(Vuu, L64);
    k_solveK<<<65, 256, 0, stream>>>(L64, S, btv, K0, k0v);
    k_gemm<<<NB / 64, 256, 0, stream>>>(g0, K0, k0v, (float*)d_out);
}

// Round 9
// 2076.842 us; speedup vs baseline: 2.0575x; 2.0575x over previous
//
#include <hip/hip_runtime.h>

// KoopmanLQR via structured doubling (SDA): 8 iterations replace 255 Riccati steps.
// Round 11: revert round-10's sc1 experiment (uncached scalar traffic: WRITE_SIZE
// 28->106MB, regressed). Base = round-9 passing kernel (3040us). Changes:
// (1) fused 12-phase schedule (was 17): inv64(0) inside formMt; inv64(J+1) runs
//     inside P2c(J) on WG0 (tile (J+1,J+1) excluded from other workers); pivot-row
//     materialization phases eliminated via per-step Trs buffers + rb==J-1
//     redirect (P2c's read-modify-write materializes the row as a side effect);
//     apply reads row-3 of M^-1 straight from Trs_3.   137 -> 97 barriers.
// (2) float4-vectorized LDS staging everywhere (was scalar, 4x the vmem instrs).
// K=256, U=64, BATCH=131072. All fp32.

#define KD 256
#define UD 64
#define NB 131072
#define NWG 50   // grid size (max phase width = upd1's 50); all WGs co-resident
#define NIT 8

// ---------------- parallel-flag grid barrier (round-9, proven) ----------------
__device__ __forceinline__ void gbar(unsigned* bar, unsigned gen) {
    __syncthreads();
    if (threadIdx.x == 0)
        __hip_atomic_store(&bar[16 + 16 * blockIdx.x], gen, __ATOMIC_RELEASE,
                           __HIP_MEMORY_SCOPE_AGENT);
    if (blockIdx.x == 0) {
        if (threadIdx.x < NWG) {
            int p = 0;
            while (__hip_atomic_load(&bar[16 + 16 * threadIdx.x], __ATOMIC_RELAXED,
                                     __HIP_MEMORY_SCOPE_AGENT) < gen) {
                __builtin_amdgcn_s_sleep(1);
                if (((++p) & 255) == 0)
                    (void)__hip_atomic_load(&bar[16 + 16 * threadIdx.x], __ATOMIC_ACQUIRE,
                                            __HIP_MEMORY_SCOPE_AGENT);
            }
        }
        __syncthreads();
        if (threadIdx.x == 0) {
            __builtin_amdgcn_fence(__ATOMIC_ACQ_REL, "agent");
            __hip_atomic_store(&bar[0], gen, __ATOMIC_RELEASE, __HIP_MEMORY_SCOPE_AGENT);
        }
        __syncthreads();
    } else {
        if (threadIdx.x == 0) {
            int p = 0;
            while (__hip_atomic_load(&bar[0], __ATOMIC_RELAXED,
                                     __HIP_MEMORY_SCOPE_AGENT) < gen) {
                __builtin_amdgcn_s_sleep(2);
                if (((++p) & 255) == 0)
                    (void)__hip_atomic_load(&bar[0], __ATOMIC_ACQUIRE,
                                            __HIP_MEMORY_SCOPE_AGENT);
            }
            __builtin_amdgcn_fence(__ATOMIC_ACQUIRE, "agent");
        }
        __syncthreads();
    }
}

// ---------------- 64-deep 4x4-microkernel MAC on staged LDS tiles ----------------
__device__ __forceinline__ void mac64(const float* At, const float* Bt,
                                      float acc[4][4], int tb, int tj) {
    for (int kl = 0; kl < 64; ++kl) {
        float4 a4 = *(const float4*)&At[kl * 68 + 4 * tb];
        float4 b4 = *(const float4*)&Bt[kl * 68 + 4 * tj];
        acc[0][0] += a4.x * b4.x; acc[0][1] += a4.x * b4.y; acc[0][2] += a4.x * b4.z; acc[0][3] += a4.x * b4.w;
        acc[1][0] += a4.y * b4.x; acc[1][1] += a4.y * b4.y; acc[1][2] += a4.y * b4.z; acc[1][3] += a4.y * b4.w;
        acc[2][0] += a4.z * b4.x; acc[2][1] += a4.z * b4.y; acc[2][2] += a4.z * b4.z; acc[2][3] += a4.z * b4.w;
        acc[3][0] += a4.w * b4.x; acc[3][1] += a4.w * b4.y; acc[3][2] += a4.w * b4.z; acc[3][3] += a4.w * b4.w;
    }
}

// ---------------- in-place GJ inversion of W (64x64, stride 68); scr >= 2688 floats ----------------
__device__ void inv64(float* W, float* scr, int tid) {
    float* T16 = scr;          // 16*68
    float* C16 = scr + 1088;   // 64*20
    float* Wd  = scr + 2368;   // 16*20
    for (int Js = 0; Js < 4; ++Js) {
        if (tid < 64) {  // level-1: 16x16 scalar sweep, 1 wave, lockstep
            int r = tid >> 2, s = tid & 3;
            for (int q = 0; q < 4; ++q) {
                int e2 = tid * 4 + q, rr = e2 >> 4, cc = e2 & 15;
                Wd[rr * 20 + cc] = W[(16 * Js + rr) * 68 + 16 * Js + cc];
            }
            for (int j = 0; j < 16; ++j) {
                float piv = Wd[j * 20 + j];
                float rp = 1.f / piv;
                float4 pr = *(const float4*)&Wd[j * 20 + 4 * s];
                float colv = Wd[r * 20 + j];
                float4 mi = *(const float4*)&Wd[r * 20 + 4 * s];
                float t0 = pr.x * rp, t1 = pr.y * rp, t2 = pr.z * rp, t3 = pr.w * rp;
                float m0, m1, m2, m3;
                if (r == j) { m0 = t0; m1 = t1; m2 = t2; m3 = t3; }
                else { m0 = mi.x - colv * t0; m1 = mi.y - colv * t1;
                       m2 = mi.z - colv * t2; m3 = mi.w - colv * t3; }
                if ((j >> 2) == s) {
                    float cv = (r == j) ? rp : -colv * rp;
                    int q = j & 3;
                    if (q == 0) m0 = cv; else if (q == 1) m1 = cv;
                    else if (q == 2) m2 = cv; else m3 = cv;
                }
                *(float4*)&Wd[r * 20 + 4 * s] = make_float4(m0, m1, m2, m3);
            }
            for (int q = 0; q < 4; ++q) {
                int e2 = tid * 4 + q, rr = e2 >> 4, cc = e2 & 15;
                W[(16 * Js + rr) * 68 + 16 * Js + cc] = Wd[rr * 20 + cc];
            }
        }
        __syncthreads();
        for (int e = tid; e < 1024; e += 256) {
            int r = e >> 6, c = e & 63;
            float s0 = 0.f;
            for (int k = 0; k < 16; ++k)
                s0 += W[(16 * Js + r) * 68 + 16 * Js + k] * W[(16 * Js + k) * 68 + c];
            T16[r * 68 + c] = s0;
        }
        for (int e = tid; e < 1024; e += 256) {
            int r2 = e >> 4, c2 = e & 15;
            float s0 = 0.f;
            for (int k = 0; k < 16; ++k)
                s0 += W[r2 * 68 + 16 * Js + k] * W[(16 * Js + k) * 68 + 16 * Js + c2];
            C16[r2 * 20 + c2] = s0;
        }
        __syncthreads();
        for (int e = tid; e < 1024; e += 256) {
            int r = e >> 4, c4 = (e & 15) * 4;
            if ((r >> 4) != Js && (c4 >> 4) != Js) {
                float4 x = *(const float4*)&W[r * 68 + c4];
                for (int k = 0; k < 16; ++k) {
                    float avv = W[r * 68 + 16 * Js + k];
                    const float4 t4 = *(const float4*)&T16[k * 68 + c4];
                    x.x -= avv * t4.x; x.y -= avv * t4.y;
                    x.z -= avv * t4.z; x.w -= avv * t4.w;
                }
                *(float4*)&W[r * 68 + c4] = x;
            }
        }
        __syncthreads();
        for (int e = tid; e < 1024; e += 256) {
            int r = e >> 6, c = e & 63;
            if ((c >> 4) != Js) W[(16 * Js + r) * 68 + c] = T16[r * 68 + c];
        }
        for (int e = tid; e < 1024; e += 256) {
            int r2 = e >> 4, c2 = e & 15;
            if ((r2 >> 4) != Js) W[r2 * 68 + 16 * Js + c2] = -C16[r2 * 20 + c2];
        }
        __syncthreads();
    }
}

// ---------------- generic 64x64-tile matmul (K=256), float4 staging ----------------
// C[bi,bj] = op(A)*op(B) (+C0) (+I). Arow3: if non-null, A row-block 3 cols 0-2
// are read from Arow3[kc*4096 + r*64 + c] (apply's Trs_3 redirect).
__device__ __forceinline__ void mm_tile(float* At, float* Bt,
                                        const float* Aop, const float* Bop,
                                        const float* C0, float* C,
                                        int tra, int trb, int addI, int bi, int bj,
                                        const float* Arow3) {
    int tid = threadIdx.x;
    int tb = tid >> 4, tj = tid & 15;
    float acc[4][4] = {{0.f}};
    for (int kc = 0; kc < 4; ++kc) {
        __syncthreads();
        if (!tra) {
            for (int e = tid; e < 1024; e += 256) {
                int r = e >> 4, c4 = (e & 15) * 4;
                const float4 v = (Arow3 && bi == 3 && kc < 3)
                    ? *(const float4*)&Arow3[kc * 4096 + r * 64 + c4]
                    : *(const float4*)&Aop[(bi * 64 + r) * 256 + kc * 64 + c4];
                At[(c4 + 0) * 68 + r] = v.x; At[(c4 + 1) * 68 + r] = v.y;
                At[(c4 + 2) * 68 + r] = v.z; At[(c4 + 3) * 68 + r] = v.w;
            }
        } else {
            for (int e = tid; e < 1024; e += 256) {
                int c = e >> 4, r4 = (e & 15) * 4;
                *(float4*)&At[c * 68 + r4] =
                    *(const float4*)&Aop[(kc * 64 + c) * 256 + bi * 64 + r4];
            }
        }
        if (!trb) {
            for (int e = tid; e < 1024; e += 256) {
                int c = e >> 4, j4 = (e & 15) * 4;
                *(float4*)&Bt[c * 68 + j4] =
                    *(const float4*)&Bop[(kc * 64 + c) * 256 + bj * 64 + j4];
            }
        } else {
            for (int e = tid; e < 1024; e += 256) {
                int j = e >> 4, c4 = (e & 15) * 4;
                const float4 v = *(const float4*)&Bop[(bj * 64 + j) * 256 + kc * 64 + c4];
                Bt[(c4 + 0) * 68 + j] = v.x; Bt[(c4 + 1) * 68 + j] = v.y;
                Bt[(c4 + 2) * 68 + j] = v.z; Bt[(c4 + 3) * 68 + j] = v.w;
            }
        }
        __syncthreads();
        mac64(At, Bt, acc, tb, tj);
    }
    for (int ii = 0; ii < 4; ++ii) {
        int gi = bi * 64 + 4 * tb + ii;
        float4 o = make_float4(acc[ii][0], acc[ii][1], acc[ii][2], acc[ii][3]);
        if (C0) {
            const float4 c0 = *(const float4*)&C0[gi * 256 + bj * 64 + 4 * tj];
            o.x += c0.x; o.y += c0.y; o.z += c0.z; o.w += c0.w;
        }
        if (addI && bi == bj) {
            int d = (4 * tb + ii) - 4 * tj;
            if (d >= 0 && d < 4) ((float*)&o)[d] += 1.f;
        }
        *(float4*)&C[gi * 256 + bj * 64 + 4 * tj] = o;
    }
}

// ======================= init (also zeros the barrier state) =======================
__global__ void k_init(const float* __restrict__ ql, const float* __restrict__ rl,
                       const float* __restrict__ gg, const float* __restrict__ A,
                       float* __restrict__ H, float* __restrict__ F,
                       float* __restrict__ a, float* __restrict__ h,
                       float* __restrict__ rinv, unsigned* __restrict__ bar) {
    int idx = blockIdx.x * 256 + threadIdx.x;
    int i = idx >> 8, j = idx & 255;
    H[idx] = (i == j) ? expf(ql[i]) : 0.f;
    F[idx] = A[idx];
    if (idx < 256) { h[idx] = expf(ql[idx]) * gg[idx]; a[idx] = 0.f; }
    if (idx < 64) rinv[idx] = expf(-rl[idx]);
    if (idx < 16 + 16 * NWG) bar[idx] = 0u;
}

// ======================= the whole SDA loop, 12 phases/iteration =======================
__global__ __launch_bounds__(256) void k_sda(
    const float* A, const float* Bm,
    float* G, float* H, float* F0, float* F1, float* M,
    float* XF, float* XG, float* HXF, float* Pm,
    float* a, float* h, float* t, float* z, float* wv, float* av,
    const float* rinv, unsigned* bar) {
    __shared__ __align__(16) float SA[64 * 68];
    __shared__ __align__(16) float SB[64 * 68];
    __shared__ __align__(16) float SC[64 * 68];
    const int w = blockIdx.x;
    const int tid = threadIdx.x;
    const int tb = tid >> 4, tj = tid & 15;
    unsigned gen = 0;
    float* Trs = HXF;  // 12 tiles: Trs[(J*3+i)*4096 ...], 48K floats < 64K (HXF)
    float* Ncs = Pm;   // 3 tiles per step (overwritten each step)

    // ---- setup: G = B R^-1 B^T (16 tile WGs, K=64) ----
    if (w < 16) {
        int bi = w >> 2, bj = w & 3;
        for (int e = tid; e < 4096; e += 256) {
            int r = e >> 6, u = e & 63;
            SA[u * 68 + r] = Bm[(bi * 64 + r) * 64 + u] * rinv[u];
        }
        for (int e = tid; e < 1024; e += 256) {
            int c = e >> 4, u4 = (e & 15) * 4;
            const float4 v = *(const float4*)&Bm[(bj * 64 + c) * 64 + u4];
            SB[(u4 + 0) * 68 + c] = v.x; SB[(u4 + 1) * 68 + c] = v.y;
            SB[(u4 + 2) * 68 + c] = v.z; SB[(u4 + 3) * 68 + c] = v.w;
        }
        __syncthreads();
        float acc[4][4] = {{0.f}};
        mac64(SA, SB, acc, tb, tj);
        for (int ii = 0; ii < 4; ++ii)
            *(float4*)&G[(bi * 64 + 4 * tb + ii) * 256 + bj * 64 + 4 * tj] =
                make_float4(acc[ii][0], acc[ii][1], acc[ii][2], acc[ii][3]);
    }
    gbar(bar, ++gen);

    float* Fc = F0; float* Fn = F1;
    for (int it = 0; it < NIT; ++it) {
        // ===== C1: M = I + G*H (15 tiles to M; WG0 keeps (0,0) in LDS and inverts) ; t-MV =====
        if (w < 16) {
            int bi = w >> 2, bj = w & 3;
            float acc[4][4] = {{0.f}};
            for (int kc = 0; kc < 4; ++kc) {
                __syncthreads();
                for (int e = tid; e < 1024; e += 256) {
                    int r = e >> 4, c4 = (e & 15) * 4;
                    const float4 v = *(const float4*)&G[(bi * 64 + r) * 256 + kc * 64 + c4];
                    SA[(c4 + 0) * 68 + r] = v.x; SA[(c4 + 1) * 68 + r] = v.y;
                    SA[(c4 + 2) * 68 + r] = v.z; SA[(c4 + 3) * 68 + r] = v.w;
                }
                for (int e = tid; e < 1024; e += 256) {
                    int c = e >> 4, j4 = (e & 15) * 4;
                    *(float4*)&SB[c * 68 + j4] =
                        *(const float4*)&H[(kc * 64 + c) * 256 + bj * 64 + j4];
                }
                __syncthreads();
                mac64(SA, SB, acc, tb, tj);
            }
            if (w == 0) {
                for (int ii = 0; ii < 4; ++ii)
                    for (int jj = 0; jj < 4; ++jj) {
                        int gi = 4 * tb + ii, gj = 4 * tj + jj;
                        SC[gi * 68 + gj] = acc[ii][jj] + (gi == gj ? 1.f : 0.f);
                    }
                __syncthreads();
                inv64(SC, SA, tid);          // SC = S(0)
                for (int e = tid; e < 1024; e += 256) {
                    int r = e >> 4, c4 = (e & 15) * 4;
                    *(float4*)&M[r * 256 + c4] = *(const float4*)&SC[r * 68 + c4];
                }
            } else {
                for (int ii = 0; ii < 4; ++ii) {
                    int gi = bi * 64 + 4 * tb + ii;
                    float4 o = make_float4(acc[ii][0], acc[ii][1], acc[ii][2], acc[ii][3]);
                    if (bi == bj) {
                        int d = (4 * tb + ii) - 4 * tj;
                        if (d >= 0 && d < 4) ((float*)&o)[d] += 1.f;
                    }
                    *(float4*)&M[gi * 256 + bj * 64 + 4 * tj] = o;
                }
            }
        } else if (w == 16) {
            SA[tid] = h[tid];
            __syncthreads();
            float acc = a[tid];
            for (int j4 = 0; j4 < 64; ++j4) {    // G symmetric: use row tid
                const float4 g4 = *(const float4*)&G[tid * 256 + j4 * 4];
                acc -= g4.x * SA[j4 * 4] + g4.y * SA[j4 * 4 + 1]
                     + g4.z * SA[j4 * 4 + 2] + g4.w * SA[j4 * 4 + 3];
            }
            t[tid] = acc;
        }
        gbar(bar, ++gen);

        // ===== inversion sweep: for J = 0..3: {P2b(J)} ; {P2c(J) || WG0: upd+inv(J+1)} =====
        for (int J = 0; J < 4; ++J) {
            // ---- P2b(J): Tr tiles -> Trs_J ; Ncol tiles -> Ncs + M ----
            if (w < 3) {
                int cb = w + (w >= J ? 1 : 0);
                for (int e = tid; e < 1024; e += 256) {      // SA[k][r] = S[r][k]
                    int r = e >> 4, k4 = (e & 15) * 4;
                    const float4 v = *(const float4*)&M[(64 * J + r) * 256 + 64 * J + k4];
                    SA[(k4 + 0) * 68 + r] = v.x; SA[(k4 + 1) * 68 + r] = v.y;
                    SA[(k4 + 2) * 68 + r] = v.z; SA[(k4 + 3) * 68 + r] = v.w;
                }
                for (int e = tid; e < 1024; e += 256) {      // SB[k][c] = Mold[J][cb]
                    int k = e >> 4, c4 = (e & 15) * 4;
                    *(float4*)&SB[k * 68 + c4] =
                        *(const float4*)&M[(64 * J + k) * 256 + 64 * cb + c4];
                }
                __syncthreads();
                float acc[4][4] = {{0.f}};
                mac64(SA, SB, acc, tb, tj);
                for (int ii = 0; ii < 4; ++ii)
                    *(float4*)&Trs[(J * 3 + w) * 4096 + (4 * tb + ii) * 64 + 4 * tj] =
                        make_float4(acc[ii][0], acc[ii][1], acc[ii][2], acc[ii][3]);
            } else if (w < 6) {
                int i = w - 3;
                int rb = i + (i >= J ? 1 : 0);
                for (int e = tid; e < 1024; e += 256) {      // SA[k][r] = Mcur[rb][J][r][k]
                    int r = e >> 4, k4 = (e & 15) * 4;
                    const float4 v = (rb == J - 1)
                        ? *(const float4*)&Trs[((J - 1) * 3 + (J - 1)) * 4096 + r * 64 + k4]
                        : *(const float4*)&M[(64 * rb + r) * 256 + 64 * J + k4];
                    SA[(k4 + 0) * 68 + r] = v.x; SA[(k4 + 1) * 68 + r] = v.y;
                    SA[(k4 + 2) * 68 + r] = v.z; SA[(k4 + 3) * 68 + r] = v.w;
                }
                for (int e = tid; e < 1024; e += 256) {      // SB[k][c] = S[k][c]
                    int k = e >> 4, c4 = (e & 15) * 4;
                    *(float4*)&SB[k * 68 + c4] =
                        *(const float4*)&M[(64 * J + k) * 256 + 64 * J + c4];
                }
                __syncthreads();
                float acc[4][4] = {{0.f}};
                mac64(SA, SB, acc, tb, tj);
                for (int ii = 0; ii < 4; ++ii) {
                    float4 o = make_float4(-acc[ii][0], -acc[ii][1], -acc[ii][2], -acc[ii][3]);
                    *(float4*)&Ncs[i * 4096 + (4 * tb + ii) * 64 + 4 * tj] = o;
                    *(float4*)&M[(64 * rb + 4 * tb + ii) * 256 + 64 * J + 4 * tj] = o;
                }
            }
            gbar(bar, ++gen);

            // ---- P2c(J) (tiles, minus (J+1,J+1)) || WG0: update (J+1,J+1) + inv64(J+1) ----
            if (w == 0) {
                if (J < 3) {
                    int q = J + 1;
                    for (int e = tid; e < 1024; e += 256) {  // SA[k][r] = Ncol[q][r][k]
                        int r = e >> 4, k4 = (e & 15) * 4;
                        const float4 v = *(const float4*)&Ncs[J * 4096 + r * 64 + k4];
                        SA[(k4 + 0) * 68 + r] = v.x; SA[(k4 + 1) * 68 + r] = v.y;
                        SA[(k4 + 2) * 68 + r] = v.z; SA[(k4 + 3) * 68 + r] = v.w;
                    }
                    for (int e = tid; e < 1024; e += 256) {  // SB[k][c] = Mold[J][q]
                        int k = e >> 4, c4 = (e & 15) * 4;
                        *(float4*)&SB[k * 68 + c4] =
                            *(const float4*)&M[(64 * J + k) * 256 + 64 * q + c4];
                    }
                    __syncthreads();
                    float acc[4][4] = {{0.f}};
                    mac64(SA, SB, acc, tb, tj);
                    for (int ii = 0; ii < 4; ++ii) {
                        const float4 b4 =
                            *(const float4*)&M[(64 * q + 4 * tb + ii) * 256 + 64 * q + 4 * tj];
                        *(float4*)&SC[(4 * tb + ii) * 68 + 4 * tj] =
                            make_float4(b4.x + acc[ii][0], b4.y + acc[ii][1],
                                        b4.z + acc[ii][2], b4.w + acc[ii][3]);
                    }
                    __syncthreads();
                    inv64(SC, SA, tid);      // SC = S(J+1)
                    for (int e = tid; e < 1024; e += 256) {
                        int r = e >> 4, c4 = (e & 15) * 4;
                        *(float4*)&M[(64 * q + r) * 256 + 64 * q + c4] =
                            *(const float4*)&SC[r * 68 + c4];
                    }
                }
            } else if (w <= 9) {
                int tIdx = w - 1, ri = tIdx / 3, ci = tIdx % 3;
                int rb = ri + (ri >= J ? 1 : 0), cb = ci + (ci >= J ? 1 : 0);
                if (!(J < 3 && rb == J + 1 && cb == J + 1)) {
                    for (int e = tid; e < 1024; e += 256) {  // SA[k][r] = Ncol[rb][r][k]
                        int r = e >> 4, k4 = (e & 15) * 4;
                        const float4 v = *(const float4*)&Ncs[ri * 4096 + r * 64 + k4];
                        SA[(k4 + 0) * 68 + r] = v.x; SA[(k4 + 1) * 68 + r] = v.y;
                        SA[(k4 + 2) * 68 + r] = v.z; SA[(k4 + 3) * 68 + r] = v.w;
                    }
                    for (int e = tid; e < 1024; e += 256) {  // SB[k][c] = Mold[J][cb]
                        int k = e >> 4, c4 = (e & 15) * 4;
                        *(float4*)&SB[k * 68 + c4] =
                            *(const float4*)&M[(64 * J + k) * 256 + 64 * cb + c4];
                    }
                    __syncthreads();
                    float acc[4][4] = {{0.f}};
                    mac64(SA, SB, acc, tb, tj);
                    for (int ii = 0; ii < 4; ++ii) {
                        // base: current value of block (rb,cb); row J-1 lives in Trs_{J-1}
                        const float4 b4 = (rb == J - 1 && cb != rb)
                            ? *(const float4*)&Trs[((J - 1) * 3 + (cb - (cb > J - 1 ? 1 : 0))) * 4096
                                                   + (4 * tb + ii) * 64 + 4 * tj]
                            : *(const float4*)&M[(64 * rb + 4 * tb + ii) * 256 + 64 * cb + 4 * tj];
                        *(float4*)&M[(64 * rb + 4 * tb + ii) * 256 + 64 * cb + 4 * tj] =
                            make_float4(b4.x + acc[ii][0], b4.y + acc[ii][1],
                                        b4.z + acc[ii][2], b4.w + acc[ii][3]);
                    }
                }
            }
            gbar(bar, ++gen);
        }

        // ===== C10: apply: XF = M^-1 F, XG = M^-1 G, z = M^-1 t (row-3 from Trs_3) =====
        if (w < 16) {
            mm_tile(SA, SB, M, Fc, nullptr, XF, 0, 0, 0, w >> 2, w & 3, Trs + 9 * 4096);
        } else if (w < 32) {
            mm_tile(SA, SB, M, G, nullptr, XG, 0, 0, 0, (w - 16) >> 2, (w - 16) & 3, Trs + 9 * 4096);
        } else if (w == 32) {
            SA[tid] = t[tid];
            __syncthreads();
            float acc = 0.f;
            int rb3 = tid >> 6, rr = tid & 63;
            for (int cb = 0; cb < 4; ++cb) {
                const float* src = (rb3 == 3 && cb < 3)
                    ? &Trs[(9 + cb) * 4096 + rr * 64]
                    : &M[tid * 256 + cb * 64];
                for (int j4 = 0; j4 < 16; ++j4) {
                    const float4 m4 = *(const float4*)&src[j4 * 4];
                    acc += m4.x * SA[cb * 64 + j4 * 4] + m4.y * SA[cb * 64 + j4 * 4 + 1]
                         + m4.z * SA[cb * 64 + j4 * 4 + 2] + m4.w * SA[cb * 64 + j4 * 4 + 3];
                }
            }
            z[tid] = acc;
        }
        gbar(bar, ++gen);

        // ===== C11: upd1 =====
        if (w < 16) {
            mm_tile(SA, SB, Fc, XF, nullptr, Fn, 0, 0, 0, w >> 2, w & 3, nullptr);
        } else if (w < 32) {
            mm_tile(SA, SB, H, XF, nullptr, HXF, 0, 0, 0, (w - 16) >> 2, (w - 16) & 3, nullptr);
        } else if (w < 48) {
            mm_tile(SA, SB, Fc, XG, nullptr, Pm, 0, 0, 0, (w - 32) >> 2, (w - 32) & 3, nullptr);
        } else if (w == 48) {
            SA[tid] = z[tid];
            __syncthreads();
            float acc = h[tid];
            for (int j4 = 0; j4 < 64; ++j4) {    // H symmetric: row tid
                const float4 h4 = *(const float4*)&H[tid * 256 + j4 * 4];
                acc += h4.x * SA[j4 * 4] + h4.y * SA[j4 * 4 + 1]
                     + h4.z * SA[j4 * 4 + 2] + h4.w * SA[j4 * 4 + 3];
            }
            wv[tid] = acc;
        } else if (w == 49) {
            SA[tid] = z[tid];
            __syncthreads();
            float acc = 0.f;
            for (int j4 = 0; j4 < 64; ++j4) {
                const float4 f4v = *(const float4*)&Fc[tid * 256 + j4 * 4];
                acc += f4v.x * SA[j4 * 4] + f4v.y * SA[j4 * 4 + 1]
                     + f4v.z * SA[j4 * 4 + 2] + f4v.w * SA[j4 * 4 + 3];
            }
            av[tid] = acc;
        }
        gbar(bar, ++gen);

        // ===== C12: upd2 =====
        if (w < 16) {
            mm_tile(SA, SB, Fc, HXF, H, H, 1, 0, 0, w >> 2, w & 3, nullptr);
        } else if (w < 32) {
            mm_tile(SA, SB, Pm, Fc, G, G, 0, 1, 0, (w - 16) >> 2, (w - 16) & 3, nullptr);
        } else if (w == 32) {
            SA[tid] = wv[tid];
            __syncthreads();
            float acc = h[tid];
            for (int p = 0; p < 256; ++p) acc += Fc[p * 256 + tid] * SA[p];
            h[tid] = acc;
            a[tid] += av[tid];
        }
        gbar(bar, ++gen);
        float* tmp = Fc; Fc = Fn; Fn = tmp;
    }
}

// ======================= final gains =======================
__global__ void k_btv(const float* __restrict__ B, const float* __restrict__ V,
                      const float* __restrict__ v, float* __restrict__ BtV,
                      float* __restrict__ btv) {
    if (blockIdx.x < 64) {
        int idx = blockIdx.x * 256 + threadIdx.x;
        int i = idx >> 8, q = idx & 255;
        float acc = 0.f;
        for (int p2 = 0; p2 < 256; ++p2) acc += B[p2 * 64 + i] * V[p2 * 256 + q];
        BtV[idx] = acc;
    } else if (threadIdx.x < 64) {
        int i = threadIdx.x;
        float acc = 0.f;
        for (int p2 = 0; p2 < 256; ++p2) acc += B[p2 * 64 + i] * v[p2];
        btv[i] = acc;
    }
}

__global__ void k_SVuu(const float* __restrict__ A, const float* __restrict__ B,
                       const float* __restrict__ rl, const float* __restrict__ BtV,
                       float* __restrict__ S, float* __restrict__ Vuu) {
    int bx = blockIdx.x;
    if (bx < 64) {
        int idx = bx * 256 + threadIdx.x;
        int i = idx >> 8, q = idx & 255;
        float acc = 0.f;
        for (int p2 = 0; p2 < 256; ++p2) acc += BtV[i * 256 + p2] * A[p2 * 256 + q];
        S[idx] = acc;
    } else {
        int tdx = (bx - 64) * 256 + threadIdx.x;
        int i = tdx >> 6, j = tdx & 63;
        float acc = (i == j) ? expf(rl[i]) : 0.f;
        for (int p2 = 0; p2 < 256; ++p2) acc += BtV[i * 256 + p2] * B[p2 * 64 + j];
        Vuu[tdx] = acc;
    }
}

// 64x64 SPD Cholesky, 1 WG
__global__ void k_chol(const float* __restrict__ Vuu, float* __restrict__ L) {
    __shared__ float Msh[64 * 64];
    int tid = threadIdx.x;
    for (int e = tid; e < 4096; e += 256) Msh[e] = Vuu[e];
    __syncthreads();
    int i = tid & 63, c = tid >> 6;
    for (int j = 0; j < 64; ++j) {
        if (tid == 0) Msh[j * 64 + j] = sqrtf(Msh[j * 64 + j]);
        __syncthreads();
        float d = Msh[j * 64 + j];
        if (c == 0 && i > j) Msh[i * 64 + j] /= d;
        __syncthreads();
        if (i > j) {
            float lij = Msh[i * 64 + j];
            for (int k = j + 1 + c; k <= i; k += 4)
                Msh[i * 64 + k] -= lij * Msh[k * 64 + j];
        }
        __syncthreads();
    }
    for (int e = tid; e < 4096; e += 256) {
        int r = e >> 6, k = e & 63;
        L[e] = (k <= r) ? Msh[e] : 0.f;
    }
}

// K0 = Vuu^-1 S, k0 = Vuu^-1 btv (fwd+bwd via wave shuffles)
__global__ void k_solveK(const float* __restrict__ L, const float* __restrict__ S,
                         const float* __restrict__ btv,
                         float* __restrict__ K0, float* __restrict__ k0) {
    int w = (blockIdx.x * 256 + threadIdx.x) >> 6;
    int lane = threadIdx.x & 63;
    if (w >= 257) return;
    float x = (w < 256) ? S[lane * 256 + w] : btv[lane];
    for (int a = 0; a < 64; ++a) {
        float val = (lane < a) ? L[a * 64 + lane] * x : 0.f;
        for (int o = 32; o > 0; o >>= 1) val += __shfl_xor(val, o, 64);
        float xa = (__shfl(x, a, 64) - val) / L[a * 64 + a];
        if (lane == a) x = xa;
    }
    for (int a = 63; a >= 0; --a) {
        float val = (lane > a) ? L[lane * 64 + a] * x : 0.f;
        for (int o = 32; o > 0; o >>= 1) val += __shfl_xor(val, o, 64);
        float xa = (__shfl(x, a, 64) - val) / L[a * 64 + a];
        if (lane == a) x = xa;
    }
    if (w < 256) K0[lane * 256 + w] = x;
    else k0[lane] = x;
}

// u = clip(-g0 @ K0^T + k0)
__global__ __launch_bounds__(256) void k_gemm(const float* __restrict__ g0,
                                              const float* __restrict__ K0,
                                              const float* __restrict__ k0,
                                              float* __restrict__ out) {
    __shared__ __align__(16) float g0t[64 * 68];
    __shared__ __align__(16) float kt[64 * 68];
    int tid = threadIdx.x;
    int base = blockIdx.x * 64;
    int tb = tid >> 4;
    int tj = tid & 15;
    float acc[4][4] = {{0.f}};
    for (int kc = 0; kc < 4; ++kc) {
        __syncthreads();
        for (int e = tid; e < 4096; e += 256) {
            int r = e >> 6, kl = e & 63;
            g0t[kl * 68 + r] = g0[(base + r) * 256 + kc * 64 + kl];
        }
        for (int e = tid; e < 4096; e += 256) {
            int j = e >> 6, kl = e & 63;
            kt[kl * 68 + j] = K0[j * 256 + kc * 64 + kl];
        }
        __syncthreads();
        for (int kl = 0; kl < 64; ++kl) {
            float4 g = *(const float4*)&g0t[kl * 68 + 4 * tb];
            float4 kv = *(const float4*)&kt[kl * 68 + 4 * tj];
            acc[0][0] += g.x * kv.x; acc[0][1] += g.x * kv.y; acc[0][2] += g.x * kv.z; acc[0][3] += g.x * kv.w;
            acc[1][0] += g.y * kv.x; acc[1][1] += g.y * kv.y; acc[1][2] += g.y * kv.z; acc[1][3] += g.y * kv.w;
            acc[2][0] += g.z * kv.x; acc[2][1] += g.z * kv.y; acc[2][2] += g.z * kv.z; acc[2][3] += g.z * kv.w;
            acc[3][0] += g.w * kv.x; acc[3][1] += g.w * kv.y; acc[3][2] += g.w * kv.z; acc[3][3] += g.w * kv.w;
        }
    }
    float c0 = k0[4 * tj + 0], c1 = k0[4 * tj + 1], c2 = k0[4 * tj + 2], c3 = k0[4 * tj + 3];
    for (int i = 0; i < 4; ++i) {
        float4 o;
        o.x = fminf(1.0f, fmaxf(-1.0f, c0 - acc[i][0]));
        o.y = fminf(1.0f, fmaxf(-1.0f, c1 - acc[i][1]));
        o.z = fminf(1.0f, fmaxf(-1.0f, c2 - acc[i][2]));
        o.w = fminf(1.0f, fmaxf(-1.0f, c3 - acc[i][3]));
        *(float4*)&out[(base + 4 * tb + i) * 64 + 4 * tj] = o;
    }
}

extern "C" void kernel_launch(void* const* d_in, const int* in_sizes, int n_in,
                              void* d_out, int out_size, void* d_ws, size_t ws_size,
                              hipStream_t stream) {
    const float* g0 = (const float*)d_in[0];
    const float* A  = (const float*)d_in[1];
    const float* B  = (const float*)d_in[2];
    const float* ql = (const float*)d_in[3];
    const float* rl = (const float*)d_in[4];
    const float* gg = (const float*)d_in[5];
    // d_in[6] = T == 256, hardcoded (log2 T = 8 doublings).

    float* ws = (float*)d_ws;
    float* G    = ws;             // 65536
    float* H    = G    + 65536;
    float* F0   = H    + 65536;
    float* F1   = F0   + 65536;
    float* M    = F1   + 65536;
    float* XF   = M    + 65536;
    float* XG   = XF   + 65536;
    float* HXF  = XG   + 65536;   // aliased as Trs (48K floats) during inversion
    float* P    = HXF  + 65536;   // aliased as Ncs scratch during inversion
    float* BtV  = P    + 65536;   // 16384
    float* S    = BtV  + 16384;   // 16384
    float* K0   = S    + 16384;   // 16384
    float* Vuu  = K0   + 16384;   // 4096
    float* L64  = Vuu  + 4096;    // 4096
    float* a    = L64  + 4096;    // 256
    float* h    = a    + 256;     // 256
    float* t    = h    + 256;     // 256
    float* z    = t    + 256;     // 256
    float* wv   = z    + 256;     // 256
    float* av   = wv   + 256;     // 256
    float* rinv = av   + 256;     // 64
    float* btv  = rinv + 64;      // 64
    float* k0v  = btv  + 64;      // 64
    unsigned* bar = (unsigned*)(k0v + 64);  // 16 + 16*NWG u32 barrier state

    k_init<<<256, 256, 0, stream>>>(ql, rl, gg, A, H, F0, a, h, rinv, bar);
    k_sda<<<NWG, 256, 0, stream>>>(A, B, G, H, F0, F1, M, XF, XG, HXF, P,
                                   a, h, t, z, wv, av, rinv, bar);

    // gains from V = H_8, v = h_8
    k_btv<<<65, 256, 0, stream>>>(B, H, h, BtV, btv);
    k_SVuu<<<80, 256, 0, stream>>>(A, B, rl, BtV, S, Vuu);
    k_chol<<<1, 256, 0, stream>>>(Vuu, L64);
    k_solveK<<<65, 256, 0, stream>>>(L64, S, btv, K0, k0v);
    k_gemm<<<NB / 64, 256, 0, stream>>>(g0, K0, k0v, (float*)d_out);
}